// Round 9
// baseline (467.516 us; speedup 1.0000x reference)
//
#include <hip/hip_runtime.h>
#include <stdint.h>

#define TOKENS 8192
#define DIM    1024
#define NEXP   8
#define NASSIGN (TOKENS*2)
#define BK     64          // K-depth of LDS tile (32 KB total LDS)
#define NKT    (DIM/BK)    // 16 K-steps
#define G1BLK  1088        // gemm1 jobs (17 m-slots x 8 XCDs x 8 n-tiles)

// ---- control block indices (ints) ----
#define C_CNT   0    // gate-completion counter (memset to 0 by kernel_launch)
#define C_ROW   16   // 9: per-expert row prefix (row_start), [8]=16384
#define C_TILE  25   // 9: per-expert m-tile prefix
#define C_TOTAL 34   // total m-tiles

// ---- workspace layout (bytes) ----
#define WS_CTRL  0
#define WS_TOPE  1024
#define WS_TOPW  (WS_TOPE + NASSIGN*4)
#define WS_PTOK  (WS_TOPW + NASSIGN*4)
#define WS_AROW  (WS_PTOK + NASSIGN*4)
#define WS_XB    (WS_AROW + NASSIGN*4)                 // 256-aligned
#define WS_W1T   (WS_XB  + (size_t)TOKENS*DIM*2)
#define WS_W2T   (WS_W1T + (size_t)NEXP*DIM*DIM*2)
#define WS_H     (WS_W2T + (size_t)NEXP*DIM*DIM*2)
// ye (bf16, 16384x1024 = 32 MiB) overlays xb+w1t, both dead by gemm2 time:
#define WS_YE    WS_XB

#define WGLD (DIM + 4)   // padded LDS row for Wg^T staging (bank-conflict-free)

typedef __attribute__((ext_vector_type(8))) short short8;
typedef __attribute__((ext_vector_type(4))) float floatx4;

__device__ __forceinline__ uint32_t bfr(float f) {   // fp32 -> bf16 bits, RNE
  uint32_t v = __float_as_uint(f);
  return (v + 0x7FFFu + ((v >> 16) & 1u)) >> 16;
}
__device__ __forceinline__ float b2f(uint32_t u) { return __uint_as_float(u << 16); }

__device__ __forceinline__ void load_lds16(const void* g, void* l) {
  __builtin_amdgcn_global_load_lds(
      (const __attribute__((address_space(1))) uint32_t*)g,
      (__attribute__((address_space(3))) uint32_t*)l, 16, 0, 0);
}

// ---- shared convw tile body: dst[f][d] = bf16(src[d][f]), one 64x64 tile ----
__device__ __forceinline__ void convw_tile(
    const float* __restrict__ src, uint16_t* __restrict__ dst,
    int d0, int f0, uint16_t (*tile)[68], int t) {
  int col = t & 63, rb = (t >> 6) * 16;
  #pragma unroll
  for (int i = 0; i < 16; i++) {
    int dr = rb + i;
    tile[dr][col] = (uint16_t)bfr(src[(size_t)(d0+dr)*DIM + f0 + col]);
  }
  __syncthreads();
  int dg = t & 15, frb = t >> 4;         // 4 bf16 along d per thread, 16 f-rows/pass
  #pragma unroll
  for (int i = 0; i < 4; i++) {
    int fr = frb + i * 16;
    uint32_t c0 = tile[dg*4+0][fr], c1 = tile[dg*4+1][fr];
    uint32_t c2 = tile[dg*4+2][fr], c3 = tile[dg*4+3][fr];
    uint2 v;
    v.x = c0 | (c1 << 16);
    v.y = c2 | (c3 << 16);
    *(uint2*)&dst[(size_t)(f0+fr)*DIM + d0 + dg*4] = v;
  }
}

// ---------------- D1: gating (0..2047) ∥ W1-transpose (2048..4095) + inline route ----
// Routing runs in the LAST-FINISHING gate block (device-scope atomic counter +
// release/acquire threadfence — the exact fence pattern correctness-proven in
// R7's barrier, minus the spin). It overlaps the remaining transpose blocks,
// deleting the route dispatch AND its ~18us boundary.
__global__ __launch_bounds__(256) void prep_kernel(
    const float* __restrict__ x, const float* __restrict__ Wg,
    const float* __restrict__ bg, float* __restrict__ gate_out,
    int* __restrict__ top_e, float* __restrict__ top_w,
    uint16_t* __restrict__ xb,
    const float* __restrict__ W1, uint16_t* __restrict__ W1T,
    int* __restrict__ ctrl, int* __restrict__ ptok, int* __restrict__ arow) {
  __shared__ __align__(16) char smem[NEXP * WGLD * 4];   // 32.9 KB union
  __shared__ int scnt[NEXP];
  __shared__ int rowstart[NEXP];
  __shared__ int is_last;
  int t = threadIdx.x;

  if (blockIdx.x >= 2048) {
    int cb = blockIdx.x - 2048;            // 0..2047: W1 only
    int m  = cb >> 8;                      // 8 matrices
    int d0 = ((cb >> 4) & 15) * 64, f0 = (cb & 15) * 64;
    convw_tile(W1 + (size_t)m*DIM*DIM, W1T + (size_t)m*DIM*DIM,
               d0, f0, (uint16_t (*)[68])smem, t);
    return;
  }

  // ---------- gateconv: 1 wave per token, 4 tokens/block ----------
  {
    float* wgs = (float*)smem;             // wgs[e*WGLD + d] = Wg[d][e]
    #pragma unroll
    for (int k = 0; k < 32; k++) {
      int i = k * 256 + t;                 // coalesced read of Wg flat
      float v = Wg[i];
      wgs[(i & 7) * WGLD + (i >> 3)] = v;  // bank = 4*(i&7)+(i>>3): 2-way, free
    }
    __syncthreads();

    int wave = t >> 6, lane = t & 63;
    int tok = blockIdx.x * 4 + wave;
    const float4* xr = (const float4*)(x + (size_t)tok * DIM);
    uint2* xw = (uint2*)(xb + (size_t)tok * DIM);

    float4 acc[NEXP];
    #pragma unroll
    for (int e = 0; e < NEXP; e++) acc[e] = make_float4(0.f, 0.f, 0.f, 0.f);

    #pragma unroll
    for (int c = 0; c < 4; c++) {
      float4 xv = xr[c * 64 + lane];
      uint2 o;
      o.x = bfr(xv.x) | (bfr(xv.y) << 16);
      o.y = bfr(xv.z) | (bfr(xv.w) << 16);
      xw[c * 64 + lane] = o;
      int d0 = (c * 64 + lane) * 4;
      #pragma unroll
      for (int e = 0; e < NEXP; e++) {
        float4 wv = *(const float4*)&wgs[e * WGLD + d0];
        acc[e].x = fmaf(xv.x, wv.x, acc[e].x);
        acc[e].y = fmaf(xv.y, wv.y, acc[e].y);
        acc[e].z = fmaf(xv.z, wv.z, acc[e].z);
        acc[e].w = fmaf(xv.w, wv.w, acc[e].w);
      }
    }
    float s[NEXP];
    #pragma unroll
    for (int e = 0; e < NEXP; e++) s[e] = (acc[e].x + acc[e].y) + (acc[e].z + acc[e].w);
    #pragma unroll
    for (int off = 32; off > 0; off >>= 1) {
      #pragma unroll
      for (int e = 0; e < NEXP; e++) s[e] += __shfl_xor(s[e], off);
    }
    if (lane == 0) {
      float lg[NEXP], p[NEXP];
      float mx = -1e30f;
      #pragma unroll
      for (int e = 0; e < NEXP; e++) { lg[e] = s[e] + bg[e]; mx = fmaxf(mx, lg[e]); }
      float sum = 0.f;
      #pragma unroll
      for (int e = 0; e < NEXP; e++) { p[e] = expf(lg[e] - mx); sum += p[e]; }
      float inv = 1.f / sum;
      #pragma unroll
      for (int e = 0; e < NEXP; e++) p[e] *= inv;
      float4* go = (float4*)(gate_out + (size_t)tok * NEXP);
      go[0] = make_float4(p[0], p[1], p[2], p[3]);
      go[1] = make_float4(p[4], p[5], p[6], p[7]);
      int i1 = 0;
      #pragma unroll
      for (int e = 1; e < NEXP; e++) if (p[e] > p[i1]) i1 = e;
      int i2 = (i1 == 0) ? 1 : 0;
      #pragma unroll
      for (int e = 0; e < NEXP; e++) if (e != i1 && p[e] > p[i2]) i2 = e;
      float ev = expf(p[i2] - p[i1]);      // softmax over the two top probs
      float w1 = 1.f / (1.f + ev), w2 = ev / (1.f + ev);
      top_e[2*tok]   = i1; top_e[2*tok+1] = i2;
      top_w[2*tok]   = w1; top_w[2*tok+1] = w2;
    }
  }

  // ---------- last-gate-block election (release fences + device atomic) ------
  __threadfence();                         // per-thread release (R7-proven)
  __syncthreads();                         // drains all waves' stores first
  if (t == 0) {
    int old = __hip_atomic_fetch_add(&ctrl[C_CNT], 1, __ATOMIC_ACQ_REL,
                                     __HIP_MEMORY_SCOPE_AGENT);
    is_last = (old == 2047);
  }
  __syncthreads();
  if (!is_last) return;
  __threadfence();                         // acquire: invalidate before reading tope

  // ---------- route (256 threads, R4-verbatim body) ----------
  int* sc = (int*)smem;                    // sc[e*256 + t], 8 KB
  int cnt[NEXP];
  #pragma unroll
  for (int e = 0; e < NEXP; e++) cnt[e] = 0;
  for (int j = 0; j < 64; j++) {           // 64 assignments per thread
    int e = top_e[t * 64 + j];
    cnt[e]++;
  }
  #pragma unroll
  for (int e = 0; e < NEXP; e++) sc[e * 256 + t] = cnt[e];
  __syncthreads();
  int wave = t >> 6, lane = t & 63;
  for (int ee = wave; ee < NEXP; ee += 4) { // 4 waves, 2 experts each
    int running = 0;
    for (int chunk = 0; chunk < 4; chunk++) {
      int idx = ee * 256 + chunk * 64 + lane;
      int v = sc[idx];
      int incl = v;
      #pragma unroll
      for (int off = 1; off < 64; off <<= 1) {
        int u = __shfl_up(incl, off);
        if (lane >= off) incl += u;
      }
      sc[idx] = running + incl - v;        // exclusive prefix
      running += __shfl(incl, 63);
    }
    if (lane == 0) scnt[ee] = running;
  }
  __syncthreads();
  if (t == 0) {
    int rs = 0, ts = 0;
    for (int e = 0; e < NEXP; e++) {
      ctrl[C_ROW + e] = rs;
      ctrl[C_TILE + e] = ts;
      rowstart[e] = rs;
      int c = scnt[e];
      rs += c;
      ts += (c + 127) >> 7;
    }
    ctrl[C_ROW + NEXP] = rs;
    ctrl[C_TILE + NEXP] = ts;
    ctrl[C_TOTAL] = ts;
  }
  __syncthreads();
  int off[NEXP];
  #pragma unroll
  for (int e = 0; e < NEXP; e++) off[e] = rowstart[e] + sc[e * 256 + t];
  for (int j = 0; j < 64; j++) {
    int i = t * 64 + j;
    int e = top_e[i];
    int pos = off[e]++;
    ptok[pos] = i >> 1;
    arow[i] = pos;                         // inverse permutation: assignment -> row
  }
}

// ---------------- GEMM block schedule ----------------
__device__ __forceinline__ bool sched_map(const int* ctrl, int bid,
                                          int& mtile, int& n0) {
  int total = ctrl[C_TOTAL];           // 128..135
  int spx = (total + 7) >> 3;          // slots per XCD: 16 or 17
  int xcd = bid & 7, j = bid >> 3;
  int slot = j >> 3;
  if (slot >= spx) return false;
  mtile = xcd * spx + slot;
  n0 = (j & 7) * 128;
  return mtile < total;
}

// ---------------- GEMM1 + W2-transpose in one dispatch (R8-verbatim) ----------
__global__ __launch_bounds__(256, 2) void gemm1_kernel(
    const uint16_t* __restrict__ xb, const uint16_t* __restrict__ w1t,
    const float* __restrict__ b1, const int* __restrict__ ctrl,
    const int* __restrict__ ptok, uint16_t* __restrict__ h,
    const float* __restrict__ W2, uint16_t* __restrict__ w2t) {
  __shared__ __align__(16) uint16_t As[128*BK];
  __shared__ __align__(16) uint16_t Bs[128*BK];
  int t = threadIdx.x;

  if (blockIdx.x >= G1BLK) {
    int cb = blockIdx.x - G1BLK;           // 0..2047: W2 only
    int m  = cb >> 8;                      // 8 matrices
    int d0 = ((cb >> 4) & 15) * 64, f0 = (cb & 15) * 64;
    convw_tile(W2 + (size_t)m*DIM*DIM, w2t + (size_t)m*DIM*DIM,
               d0, f0, (uint16_t (*)[68])As, t);
    return;
  }

  int mtile, n0;
  if (!sched_map(ctrl, blockIdx.x, mtile, n0)) return;
  int e = 0;
  #pragma unroll
  for (int k = 1; k < NEXP; k++) if (mtile >= ctrl[C_TILE + k]) e = k;
  int row0 = ctrl[C_ROW + e] + (mtile - ctrl[C_TILE + e]) * 128;
  int rend = ctrl[C_ROW + e + 1];

  int lane = t & 63, w = t >> 6;
  const uint16_t* gA[4];
  const uint16_t* gB[4];
  #pragma unroll
  for (int i = 0; i < 4; i++) {
    int s = i * 256 + t;               // LDS slot (16B units), 1024 per matrix
    int row = s >> 3, cs = s & 7;
    int gc = cs ^ (row & 7);           // inverse XOR swizzle applied at the source
    int ar = row0 + row; if (ar > NASSIGN-1) ar = NASSIGN-1;
    int tok = ptok[ar];
    gA[i] = xb  + (size_t)tok * DIM + gc*8;
    gB[i] = w1t + (size_t)e*DIM*DIM + (size_t)(n0 + row)*DIM + gc*8;
  }
  floatx4 acc[4][4];
  #pragma unroll
  for (int mi = 0; mi < 4; mi++)
    #pragma unroll
    for (int ni = 0; ni < 4; ni++) acc[mi][ni] = (floatx4)(0.f);

  int wm = w & 1, wn = w >> 1;
  int l15 = lane & 15, lq = lane >> 4;

  for (int kt = 0; kt < NKT; kt++) {
    #pragma unroll
    for (int i = 0; i < 4; i++) {
      load_lds16(gA[i], &As[(i*256 + t) * 8]);
      load_lds16(gB[i], &Bs[(i*256 + t) * 8]);
      gA[i] += BK; gB[i] += BK;
    }
    __syncthreads();
    #pragma unroll
    for (int ks = 0; ks < 2; ks++) {
      short8 a[4], b[4];
      #pragma unroll
      for (int mi = 0; mi < 4; mi++) {
        int row = wm*64 + mi*16 + l15;
        int slot = (ks*4 + lq) ^ (row & 7);
        a[mi] = *(const short8*)&As[row*BK + slot*8];
      }
      #pragma unroll
      for (int ni = 0; ni < 4; ni++) {
        int row = wn*64 + ni*16 + l15;
        int slot = (ks*4 + lq) ^ (row & 7);
        b[ni] = *(const short8*)&Bs[row*BK + slot*8];
      }
      #pragma unroll
      for (int mi = 0; mi < 4; mi++)
        #pragma unroll
        for (int ni = 0; ni < 4; ni++)
          acc[mi][ni] = __builtin_amdgcn_mfma_f32_16x16x32_bf16(a[mi], b[ni], acc[mi][ni], 0, 0, 0);
    }
    __syncthreads();
  }
  #pragma unroll
  for (int mi = 0; mi < 4; mi++) {
    #pragma unroll
    for (int r = 0; r < 4; r++) {
      int rt = wm*64 + mi*16 + lq*4 + r;
      int ar = row0 + rt;
      if (ar < rend) {
        #pragma unroll
        for (int ni = 0; ni < 4; ni++) {
          int n = n0 + wn*64 + ni*16 + l15;
          float v = acc[mi][ni][r] + b1[e*DIM + n];
          v = fmaxf(v, 0.f);
          h[(size_t)ar*DIM + n] = (uint16_t)bfr(v);
        }
      }
    }
  }
}

// ---------------- GEMM2: ye = h @ W2 + b2, bf16 dense rows (R4-verbatim) ----------------
__global__ __launch_bounds__(256, 2) void gemm2_kernel(
    const uint16_t* __restrict__ h, const uint16_t* __restrict__ w2t,
    const float* __restrict__ b2, const int* __restrict__ ctrl,
    uint16_t* __restrict__ yeb) {
  __shared__ __align__(16) uint16_t As[128*BK];
  __shared__ __align__(16) uint16_t Bs[128*BK];
  int mtile, n0;
  if (!sched_map(ctrl, blockIdx.x, mtile, n0)) return;
  int e = 0;
  #pragma unroll
  for (int k = 1; k < NEXP; k++) if (mtile >= ctrl[C_TILE + k]) e = k;
  int row0 = ctrl[C_ROW + e] + (mtile - ctrl[C_TILE + e]) * 128;
  int rend = ctrl[C_ROW + e + 1];

  int t = threadIdx.x, lane = t & 63, w = t >> 6;
  const uint16_t* gA[4];
  const uint16_t* gB[4];
  #pragma unroll
  for (int i = 0; i < 4; i++) {
    int s = i * 256 + t;
    int row = s >> 3, cs = s & 7;
    int gc = cs ^ (row & 7);
    int ar = row0 + row; if (ar > NASSIGN-1) ar = NASSIGN-1;
    gA[i] = h   + (size_t)ar * DIM + gc*8;
    gB[i] = w2t + (size_t)e*DIM*DIM + (size_t)(n0 + row)*DIM + gc*8;
  }
  floatx4 acc[4][4];
  #pragma unroll
  for (int mi = 0; mi < 4; mi++)
    #pragma unroll
    for (int ni = 0; ni < 4; ni++) acc[mi][ni] = (floatx4)(0.f);

  int wm = w & 1, wn = w >> 1;
  int l15 = lane & 15, lq = lane >> 4;

  for (int kt = 0; kt < NKT; kt++) {
    #pragma unroll
    for (int i = 0; i < 4; i++) {
      load_lds16(gA[i], &As[(i*256 + t) * 8]);
      load_lds16(gB[i], &Bs[(i*256 + t) * 8]);
      gA[i] += BK; gB[i] += BK;
    }
    __syncthreads();
    #pragma unroll
    for (int ks = 0; ks < 2; ks++) {
      short8 a[4], b[4];
      #pragma unroll
      for (int mi = 0; mi < 4; mi++) {
        int row = wm*64 + mi*16 + l15;
        int slot = (ks*4 + lq) ^ (row & 7);
        a[mi] = *(const short8*)&As[row*BK + slot*8];
      }
      #pragma unroll
      for (int ni = 0; ni < 4; ni++) {
        int row = wn*64 + ni*16 + l15;
        int slot = (ks*4 + lq) ^ (row & 7);
        b[ni] = *(const short8*)&Bs[row*BK + slot*8];
      }
      #pragma unroll
      for (int mi = 0; mi < 4; mi++)
        #pragma unroll
        for (int ni = 0; ni < 4; ni++)
          acc[mi][ni] = __builtin_amdgcn_mfma_f32_16x16x32_bf16(a[mi], b[ni], acc[mi][ni], 0, 0, 0);
    }
    __syncthreads();
  }
  #pragma unroll
  for (int mi = 0; mi < 4; mi++) {
    #pragma unroll
    for (int r = 0; r < 4; r++) {
      int rt = wm*64 + mi*16 + lq*4 + r;
      int ar = row0 + rt;
      if (ar < rend) {
        #pragma unroll
        for (int ni = 0; ni < 4; ni++) {
          int n = n0 + wn*64 + ni*16 + l15;
          float v = acc[mi][ni][r] + b2[e*DIM + n];
          yeb[(size_t)ar*DIM + n] = (uint16_t)bfr(v);
        }
      }
    }
  }
}

// ---------------- combine: y[tok] = w0*ye[r0] + w1*ye[r1], 2 tokens/block ----------------
__global__ __launch_bounds__(256) void combine_kernel(
    const uint16_t* __restrict__ yeb, const int* __restrict__ arow,
    const float* __restrict__ top_w, float* __restrict__ y) {
  int t = threadIdx.x;
  int tok = blockIdx.x * 2 + (t >> 7);     // 128 threads per token
  int i = t & 127;                          // 8 bf16 per thread
  int r0 = arow[2*tok], r1 = arow[2*tok+1];
  float w0 = top_w[2*tok], w1 = top_w[2*tok+1];
  const uint4* a = (const uint4*)(yeb + (size_t)r0 * DIM);
  const uint4* b = (const uint4*)(yeb + (size_t)r1 * DIM);
  uint4 av = a[i], bv = b[i];
  float4* yo = (float4*)(y + (size_t)tok * DIM + i * 8);
  float4 o0, o1;
  o0.x = w0 * b2f(av.x & 0xFFFFu) + w1 * b2f(bv.x & 0xFFFFu);
  o0.y = w0 * b2f(av.x >> 16)     + w1 * b2f(bv.x >> 16);
  o0.z = w0 * b2f(av.y & 0xFFFFu) + w1 * b2f(bv.y & 0xFFFFu);
  o0.w = w0 * b2f(av.y >> 16)     + w1 * b2f(bv.y >> 16);
  o1.x = w0 * b2f(av.z & 0xFFFFu) + w1 * b2f(bv.z & 0xFFFFu);
  o1.y = w0 * b2f(av.z >> 16)     + w1 * b2f(bv.z >> 16);
  o1.z = w0 * b2f(av.w & 0xFFFFu) + w1 * b2f(bv.w & 0xFFFFu);
  o1.w = w0 * b2f(av.w >> 16)     + w1 * b2f(bv.w >> 16);
  yo[0] = o0;
  yo[1] = o1;
}

extern "C" void kernel_launch(void* const* d_in, const int* in_sizes, int n_in,
                              void* d_out, int out_size, void* d_ws, size_t ws_size,
                              hipStream_t stream) {
  const float* x  = (const float*)d_in[0];
  const float* Wg = (const float*)d_in[1];
  const float* bg = (const float*)d_in[2];
  const float* W1 = (const float*)d_in[3];
  const float* b1 = (const float*)d_in[4];
  const float* W2 = (const float*)d_in[5];
  const float* b2 = (const float*)d_in[6];
  float* out = (float*)d_out;                      // [y: 8192*1024][gate: 8192*8]
  char* ws = (char*)d_ws;

  int*      ctrl = (int*)(ws + WS_CTRL);
  int*      tope = (int*)(ws + WS_TOPE);
  float*    topw = (float*)(ws + WS_TOPW);
  int*      ptok = (int*)(ws + WS_PTOK);
  int*      arow = (int*)(ws + WS_AROW);
  uint16_t* xb   = (uint16_t*)(ws + WS_XB);
  uint16_t* w1t  = (uint16_t*)(ws + WS_W1T);
  uint16_t* w2t  = (uint16_t*)(ws + WS_W2T);
  uint16_t* hbuf = (uint16_t*)(ws + WS_H);
  uint16_t* yeb  = (uint16_t*)(ws + WS_YE);        // overlays xb+w1t (dead by then)

  // zero the gate-completion counter (graph-capture-safe; R7-proven pattern)
  hipMemsetAsync(ws, 0, 64, stream);

  // D1: gating + W1 transpose + INLINE routing (last gate block) — one dispatch
  prep_kernel<<<4096, 256, 0, stream>>>(x, Wg, bg, out + (size_t)TOKENS*DIM,
                                        tope, topw, xb, W1, w1t,
                                        ctrl, ptok, arow);
  // D2: gemm1 (blocks 0..1087) + W2 transpose (blocks 1088..3135) overlapped
  gemm1_kernel<<<G1BLK + 2048, 256, 0, stream>>>(xb, w1t, b1, ctrl, ptok, hbuf,
                                                 W2, w2t);
  // D3: gemm2 (w2t complete by D2->D3 boundary)
  gemm2_kernel<<<136*8, 256, 0, stream>>>(hbuf, w2t, b2, ctrl, yeb);
  // D4: combine
  combine_kernel<<<TOKENS/2, 256, 0, stream>>>(yeb, arow, topw, out);
}

// Round 10
// 285.209 us; speedup vs baseline: 1.6392x; 1.6392x over previous
//
#include <hip/hip_runtime.h>
#include <stdint.h>

#define TOKENS 8192
#define DIM    1024
#define NEXP   8
#define NASSIGN (TOKENS*2)
#define BK     64          // K-depth of LDS tile
#define NKT    (DIM/BK)    // 16 K-steps
// gemm tile 128x256, 512 threads, 3-buffer LDS pipeline (48KB/buf, 144KB total)
#define BUF_U16 24576      // u16 per buffer: A 128x64 (8192) + B 256x64 (16384)

// ---- control block indices (ints) ----
#define C_ROW   16   // 9: per-expert row prefix (row_start), [8]=16384
#define C_TILE  25   // 9: per-expert m-tile prefix (128-row tiles)
#define C_TOTAL 34   // total m-tiles

// ---- workspace layout (bytes) ----
#define WS_CTRL  0
#define WS_TOPE  1024
#define WS_TOPW  (WS_TOPE + NASSIGN*4)
#define WS_PTOK  (WS_TOPW + NASSIGN*4)
#define WS_AROW  (WS_PTOK + NASSIGN*4)
#define WS_XB    (WS_AROW + NASSIGN*4)                 // 256-aligned
#define WS_W1T   (WS_XB  + (size_t)TOKENS*DIM*2)
#define WS_W2T   (WS_W1T + (size_t)NEXP*DIM*DIM*2)
#define WS_H     (WS_W2T + (size_t)NEXP*DIM*DIM*2)
// ye (bf16, 16384x1024 = 32 MiB) overlays xb+w1t, both dead by gemm2 time:
#define WS_YE    WS_XB

#define WGLD (DIM + 4)   // padded LDS row for Wg^T staging (bank-conflict-free)

typedef __attribute__((ext_vector_type(8))) short short8;
typedef __attribute__((ext_vector_type(4))) float floatx4;

__device__ __forceinline__ uint32_t bfr(float f) {   // fp32 -> bf16 bits, RNE
  uint32_t v = __float_as_uint(f);
  return (v + 0x7FFFu + ((v >> 16) & 1u)) >> 16;
}
__device__ __forceinline__ float b2f(uint32_t u) { return __uint_as_float(u << 16); }

__device__ __forceinline__ void load_lds16(const void* g, void* l) {
  __builtin_amdgcn_global_load_lds(
      (const __attribute__((address_space(1))) uint32_t*)g,
      (__attribute__((address_space(3))) uint32_t*)l, 16, 0, 0);
}

// ---------------- merged preprocessing (R0-verbatim, measured-best prep) ------
// Blocks [0,2048): gating + x->bf16. Blocks [2048,6144): W1+W2 transpose.
__global__ __launch_bounds__(256) void prep_kernel(
    const float* __restrict__ x, const float* __restrict__ Wg,
    const float* __restrict__ bg, float* __restrict__ gate_out,
    int* __restrict__ top_e, float* __restrict__ top_w,
    uint16_t* __restrict__ xb,
    const float* __restrict__ W1, const float* __restrict__ W2,
    uint16_t* __restrict__ W1T, uint16_t* __restrict__ W2T) {
  __shared__ __align__(16) char smem[NEXP * WGLD * 4];   // 32.9 KB union
  int t = threadIdx.x;

  if (blockIdx.x >= 2048) {
    // ---------- convw: WT[e][f][d] = bf16(W[e][d][f]), 64x64 tiles ----------
    uint16_t (*tile)[68] = (uint16_t (*)[68])smem;
    int cb = blockIdx.x - 2048;            // 0..4095
    int m  = cb >> 8;                      // 16 matrices (8 W1 + 8 W2)
    int d0 = ((cb >> 4) & 15) * 64, f0 = (cb & 15) * 64;
    const float* src = (m < 8) ? (W1 + (size_t)m*DIM*DIM) : (W2 + (size_t)(m-8)*DIM*DIM);
    uint16_t*    dst = (m < 8) ? (W1T + (size_t)m*DIM*DIM) : (W2T + (size_t)(m-8)*DIM*DIM);
    int col = t & 63, rb = (t >> 6) * 16;
    #pragma unroll
    for (int i = 0; i < 16; i++) {
      int dr = rb + i;
      tile[dr][col] = (uint16_t)bfr(src[(size_t)(d0+dr)*DIM + f0 + col]);
    }
    __syncthreads();
    int dg = t & 15, frb = t >> 4;         // 4 bf16 along d per thread
    #pragma unroll
    for (int i = 0; i < 4; i++) {
      int fr = frb + i * 16;
      uint32_t c0 = tile[dg*4+0][fr], c1 = tile[dg*4+1][fr];
      uint32_t c2 = tile[dg*4+2][fr], c3 = tile[dg*4+3][fr];
      uint2 v;
      v.x = c0 | (c1 << 16);
      v.y = c2 | (c3 << 16);
      *(uint2*)&dst[(size_t)(f0+fr)*DIM + d0 + dg*4] = v;
    }
    return;
  }

  // ---------- gateconv: 1 wave per token, 4 tokens/block ----------
  float* wgs = (float*)smem;               // wgs[e*WGLD + d] = Wg[d][e]
  #pragma unroll
  for (int k = 0; k < 32; k++) {
    int i = k * 256 + t;                   // coalesced read of Wg flat
    float v = Wg[i];
    wgs[(i & 7) * WGLD + (i >> 3)] = v;    // bank = 4*(i&7)+(i>>3): 2-way, free
  }
  __syncthreads();

  int wave = t >> 6, lane = t & 63;
  int tok = blockIdx.x * 4 + wave;
  const float4* xr = (const float4*)(x + (size_t)tok * DIM);
  uint2* xw = (uint2*)(xb + (size_t)tok * DIM);

  float4 acc[NEXP];
  #pragma unroll
  for (int e = 0; e < NEXP; e++) acc[e] = make_float4(0.f, 0.f, 0.f, 0.f);

  #pragma unroll
  for (int c = 0; c < 4; c++) {
    float4 xv = xr[c * 64 + lane];
    uint2 o;
    o.x = bfr(xv.x) | (bfr(xv.y) << 16);
    o.y = bfr(xv.z) | (bfr(xv.w) << 16);
    xw[c * 64 + lane] = o;
    int d0 = (c * 64 + lane) * 4;
    #pragma unroll
    for (int e = 0; e < NEXP; e++) {
      float4 wv = *(const float4*)&wgs[e * WGLD + d0];
      acc[e].x = fmaf(xv.x, wv.x, acc[e].x);
      acc[e].y = fmaf(xv.y, wv.y, acc[e].y);
      acc[e].z = fmaf(xv.z, wv.z, acc[e].z);
      acc[e].w = fmaf(xv.w, wv.w, acc[e].w);
    }
  }
  float s[NEXP];
  #pragma unroll
  for (int e = 0; e < NEXP; e++) s[e] = (acc[e].x + acc[e].y) + (acc[e].z + acc[e].w);
  #pragma unroll
  for (int off = 32; off > 0; off >>= 1) {
    #pragma unroll
    for (int e = 0; e < NEXP; e++) s[e] += __shfl_xor(s[e], off);
  }
  if (lane == 0) {
    float lg[NEXP], p[NEXP];
    float mx = -1e30f;
    #pragma unroll
    for (int e = 0; e < NEXP; e++) { lg[e] = s[e] + bg[e]; mx = fmaxf(mx, lg[e]); }
    float sum = 0.f;
    #pragma unroll
    for (int e = 0; e < NEXP; e++) { p[e] = expf(lg[e] - mx); sum += p[e]; }
    float inv = 1.f / sum;
    #pragma unroll
    for (int e = 0; e < NEXP; e++) p[e] *= inv;
    float4* go = (float4*)(gate_out + (size_t)tok * NEXP);
    go[0] = make_float4(p[0], p[1], p[2], p[3]);
    go[1] = make_float4(p[4], p[5], p[6], p[7]);
    int i1 = 0;
    #pragma unroll
    for (int e = 1; e < NEXP; e++) if (p[e] > p[i1]) i1 = e;
    int i2 = (i1 == 0) ? 1 : 0;
    #pragma unroll
    for (int e = 0; e < NEXP; e++) if (e != i1 && p[e] > p[i2]) i2 = e;
    float ev = expf(p[i2] - p[i1]);        // softmax over the two top probs
    float w1 = 1.f / (1.f + ev), w2 = ev / (1.f + ev);
    top_e[2*tok]   = i1; top_e[2*tok+1] = i2;
    top_w[2*tok]   = w1; top_w[2*tok+1] = w2;
  }
}

// ---------------- deterministic routing (R0-verbatim, 1 block) ----------------
__global__ __launch_bounds__(1024) void route_kernel(
    const int* __restrict__ top_e, int* __restrict__ ctrl,
    int* __restrict__ ptok, int* __restrict__ arow) {
  __shared__ int sc[NEXP * 1024];
  __shared__ int scnt[NEXP];
  __shared__ int rowstart[NEXP];
  int t = threadIdx.x;
  int e_loc[16];
  int cnt[NEXP];
  #pragma unroll
  for (int e = 0; e < NEXP; e++) cnt[e] = 0;
  #pragma unroll
  for (int j = 0; j < 16; j++) {
    int e = top_e[t * 16 + j];
    e_loc[j] = e;
    cnt[e]++;
  }
  #pragma unroll
  for (int e = 0; e < NEXP; e++) sc[e * 1024 + t] = cnt[e];
  __syncthreads();
  int wave = t >> 6, lane = t & 63;
  if (wave < NEXP) {
    int running = 0;
    for (int chunk = 0; chunk < 16; chunk++) {
      int idx = wave * 1024 + chunk * 64 + lane;
      int v = sc[idx];
      int incl = v;
      #pragma unroll
      for (int off = 1; off < 64; off <<= 1) {
        int u = __shfl_up(incl, off);
        if (lane >= off) incl += u;
      }
      sc[idx] = running + incl - v;    // exclusive prefix
      running += __shfl(incl, 63);
    }
    if (lane == 0) scnt[wave] = running;
  }
  __syncthreads();
  if (t == 0) {
    int rs = 0, ts = 0;
    for (int e = 0; e < NEXP; e++) {
      ctrl[C_ROW + e] = rs;
      ctrl[C_TILE + e] = ts;
      rowstart[e] = rs;
      int c = scnt[e];
      rs += c;
      ts += (c + 127) >> 7;
    }
    ctrl[C_ROW + NEXP] = rs;
    ctrl[C_TILE + NEXP] = ts;
    ctrl[C_TOTAL] = ts;
  }
  __syncthreads();
  int off[NEXP];
  #pragma unroll
  for (int e = 0; e < NEXP; e++) off[e] = rowstart[e] + sc[e * 1024 + t];
  #pragma unroll
  for (int j = 0; j < 16; j++) {
    int i = t * 16 + j;
    int e = e_loc[j];
    int pos = off[e]++;
    ptok[pos] = i >> 1;
    arow[i] = pos;
  }
}

// ---------------- 128x256 GEMM, 512 threads, 3-buffer counted-vmcnt pipeline ---
// Per K-tile: ONE {vmcnt(6); s_barrier} (single asm, never drains to 0 in
// steady state) -> stage kt+2 into buf[(kt+2)%3] -> 32 MFMA/wave. Legality:
// buf[(kt+2)%3]'s old content (kt-1) was consumed by every wave before the
// barrier just crossed; vmcnt(6) = exactly kt+1's 6 in-flight loads, so kt is
// fully landed for ALL waves (each wave waits, then barrier transfers).
template<bool G1>
__device__ __forceinline__ void gemm_body(
    const int* ctrl, const int* ptok,
    const uint16_t* __restrict__ Asrc, const uint16_t* __restrict__ Bsrc,
    const float* __restrict__ bias, uint16_t* __restrict__ dst,
    uint16_t* lds) {
  int total = ctrl[C_TOTAL];             // 128..135 (128-row m-tiles)
  int jobs  = total * 4;                 // x4 n-tiles of 256
  int spx   = (jobs + 7) >> 3;           // per-XCD slots
  int xcd = blockIdx.x & 7, j = blockIdx.x >> 3;
  if (j >= spx) return;
  int li = xcd * spx + j;
  if (li >= jobs) return;
  int mtile = li >> 2, n0 = (li & 3) * 256;   // consecutive li: same A-tile (L2)
  int e = 0;
  #pragma unroll
  for (int k = 1; k < NEXP; k++) if (mtile >= ctrl[C_TILE + k]) e = k;
  int row0 = ctrl[C_ROW + e] + (mtile - ctrl[C_TILE + e]) * 128;
  int rend = ctrl[C_ROW + e + 1];

  int t = threadIdx.x, lane = t & 63, w = t >> 6;  // 8 waves
  int wm = w >> 2, wn = w & 3;                     // 2M x 4N
  int l15 = lane & 15, lq = lane >> 4;

  // staging pointers (inverse XOR swizzle at the source; LDS dest linear)
  const uint16_t* gA[2];
  const uint16_t* gB[4];
  #pragma unroll
  for (int i = 0; i < 2; i++) {
    int s = i * 512 + t;                 // A: 1024 slots (128 rows x 8)
    int row = s >> 3, gc = (s & 7) ^ (row & 7);
    int ar = row0 + row; if (ar > NASSIGN-1) ar = NASSIGN-1;
    if (G1) {
      int tok = ptok[ar];
      gA[i] = Asrc + (size_t)tok * DIM + gc*8;
    } else {
      gA[i] = Asrc + (size_t)ar * DIM + gc*8;
    }
  }
  #pragma unroll
  for (int i = 0; i < 4; i++) {
    int s = i * 512 + t;                 // B: 2048 slots (256 rows x 8)
    int row = s >> 3, gc = (s & 7) ^ (row & 7);
    gB[i] = Bsrc + (size_t)e*DIM*DIM + (size_t)(n0 + row)*DIM + gc*8;
  }

  floatx4 acc[4][4];
  #pragma unroll
  for (int mi = 0; mi < 4; mi++)
    #pragma unroll
    for (int ni = 0; ni < 4; ni++) acc[mi][ni] = (floatx4)(0.f);

  // prologue: stage K-tiles 0 and 1 (6 loads each; 12 outstanding)
  #pragma unroll
  for (int p = 0; p < 2; p++) {
    uint16_t* base = lds + p * BUF_U16;
    #pragma unroll
    for (int i = 0; i < 2; i++) { load_lds16(gA[i], base + (size_t)(i*512 + t)*8); gA[i] += BK; }
    #pragma unroll
    for (int i = 0; i < 4; i++) { load_lds16(gB[i], base + 8192 + (size_t)(i*512 + t)*8); gB[i] += BK; }
  }

  #pragma unroll
  for (int kt = 0; kt < NKT; kt++) {
    // counted wait + barrier in ONE memory-clobbered asm: no memory op
    // (ds_read/gload_lds) can be moved across it by the compiler.
    if (kt < NKT - 1) asm volatile("s_waitcnt vmcnt(6)\ns_barrier" ::: "memory");
    else              asm volatile("s_waitcnt vmcnt(0)\ns_barrier" ::: "memory");
    if (kt + 2 < NKT) {                  // stage kt+2 (6 loads, stay in flight)
      uint16_t* base = lds + ((kt + 2) % 3) * BUF_U16;
      #pragma unroll
      for (int i = 0; i < 2; i++) { load_lds16(gA[i], base + (size_t)(i*512 + t)*8); gA[i] += BK; }
      #pragma unroll
      for (int i = 0; i < 4; i++) { load_lds16(gB[i], base + 8192 + (size_t)(i*512 + t)*8); gB[i] += BK; }
    }
    const uint16_t* pA = lds + (kt % 3) * BUF_U16;
    const uint16_t* pB = pA + 8192;
    __builtin_amdgcn_s_setprio(1);
    #pragma unroll
    for (int ks = 0; ks < 2; ks++) {
      short8 a[4], b[4];
      #pragma unroll
      for (int mi = 0; mi < 4; mi++) {
        int row = wm*64 + mi*16 + l15;
        int slot = (ks*4 + lq) ^ (row & 7);
        a[mi] = *(const short8*)&pA[row*BK + slot*8];
      }
      #pragma unroll
      for (int ni = 0; ni < 4; ni++) {
        int row = wn*64 + ni*16 + l15;
        int slot = (ks*4 + lq) ^ (row & 7);
        b[ni] = *(const short8*)&pB[row*BK + slot*8];
      }
      #pragma unroll
      for (int mi = 0; mi < 4; mi++)
        #pragma unroll
        for (int ni = 0; ni < 4; ni++)
          acc[mi][ni] = __builtin_amdgcn_mfma_f32_16x16x32_bf16(a[mi], b[ni], acc[mi][ni], 0, 0, 0);
    }
    __builtin_amdgcn_s_setprio(0);
  }

  #pragma unroll
  for (int mi = 0; mi < 4; mi++) {
    #pragma unroll
    for (int r = 0; r < 4; r++) {
      int rt = wm*64 + mi*16 + lq*4 + r;
      int ar = row0 + rt;
      if (ar < rend) {
        #pragma unroll
        for (int ni = 0; ni < 4; ni++) {
          int n = n0 + wn*64 + ni*16 + l15;
          float v = acc[mi][ni][r] + bias[e*DIM + n];
          if (G1) v = fmaxf(v, 0.f);
          dst[(size_t)ar*DIM + n] = (uint16_t)bfr(v);
        }
      }
    }
  }
}

__global__ __launch_bounds__(512, 1) void gemm1_kernel(
    const uint16_t* __restrict__ xb, const uint16_t* __restrict__ w1t,
    const float* __restrict__ b1, const int* __restrict__ ctrl,
    const int* __restrict__ ptok, uint16_t* __restrict__ h) {
  __shared__ __align__(16) uint16_t lds[3 * BUF_U16];   // 144 KB
  gemm_body<true>(ctrl, ptok, xb, w1t, b1, h, lds);
}

__global__ __launch_bounds__(512, 1) void gemm2_kernel(
    const uint16_t* __restrict__ h, const uint16_t* __restrict__ w2t,
    const float* __restrict__ b2, const int* __restrict__ ctrl,
    const int* __restrict__ ptok, uint16_t* __restrict__ yeb) {
  __shared__ __align__(16) uint16_t lds[3 * BUF_U16];   // 144 KB
  gemm_body<false>(ctrl, ptok, h, w2t, b2, yeb, lds);
}

// ---------------- combine: y[tok] = w0*ye[r0] + w1*ye[r1], 2 tokens/block ----------------
__global__ __launch_bounds__(256) void combine_kernel(
    const uint16_t* __restrict__ yeb, const int* __restrict__ arow,
    const float* __restrict__ top_w, float* __restrict__ y) {
  int t = threadIdx.x;
  int tok = blockIdx.x * 2 + (t >> 7);     // 128 threads per token
  int i = t & 127;                          // 8 bf16 per thread
  int r0 = arow[2*tok], r1 = arow[2*tok+1];
  float w0 = top_w[2*tok], w1 = top_w[2*tok+1];
  const uint4* a = (const uint4*)(yeb + (size_t)r0 * DIM);
  const uint4* b = (const uint4*)(yeb + (size_t)r1 * DIM);
  uint4 av = a[i], bv = b[i];
  float4* yo = (float4*)(y + (size_t)tok * DIM + i * 8);
  float4 o0, o1;
  o0.x = w0 * b2f(av.x & 0xFFFFu) + w1 * b2f(bv.x & 0xFFFFu);
  o0.y = w0 * b2f(av.x >> 16)     + w1 * b2f(bv.x >> 16);
  o0.z = w0 * b2f(av.y & 0xFFFFu) + w1 * b2f(bv.y & 0xFFFFu);
  o0.w = w0 * b2f(av.y >> 16)     + w1 * b2f(bv.y >> 16);
  o1.x = w0 * b2f(av.z & 0xFFFFu) + w1 * b2f(bv.z & 0xFFFFu);
  o1.y = w0 * b2f(av.z >> 16)     + w1 * b2f(bv.z >> 16);
  o1.z = w0 * b2f(av.w & 0xFFFFu) + w1 * b2f(bv.w & 0xFFFFu);
  o1.w = w0 * b2f(av.w >> 16)     + w1 * b2f(bv.w >> 16);
  yo[0] = o0;
  yo[1] = o1;
}

extern "C" void kernel_launch(void* const* d_in, const int* in_sizes, int n_in,
                              void* d_out, int out_size, void* d_ws, size_t ws_size,
                              hipStream_t stream) {
  const float* x  = (const float*)d_in[0];
  const float* Wg = (const float*)d_in[1];
  const float* bg = (const float*)d_in[2];
  const float* W1 = (const float*)d_in[3];
  const float* b1 = (const float*)d_in[4];
  const float* W2 = (const float*)d_in[5];
  const float* b2 = (const float*)d_in[6];
  float* out = (float*)d_out;                      // [y: 8192*1024][gate: 8192*8]
  char* ws = (char*)d_ws;

  int*      ctrl = (int*)(ws + WS_CTRL);
  int*      tope = (int*)(ws + WS_TOPE);
  float*    topw = (float*)(ws + WS_TOPW);
  int*      ptok = (int*)(ws + WS_PTOK);
  int*      arow = (int*)(ws + WS_AROW);
  uint16_t* xb   = (uint16_t*)(ws + WS_XB);
  uint16_t* w1t  = (uint16_t*)(ws + WS_W1T);
  uint16_t* w2t  = (uint16_t*)(ws + WS_W2T);
  uint16_t* hbuf = (uint16_t*)(ws + WS_H);
  uint16_t* yeb  = (uint16_t*)(ws + WS_YE);        // overlays xb+w1t (dead by then)

  // D1: merged gating + x->bf16 + W1/W2 transpose (R0-verbatim prep)
  prep_kernel<<<6144, 256, 0, stream>>>(x, Wg, bg, out + (size_t)TOKENS*DIM,
                                        tope, topw, xb, W1, W2, w1t, w2t);
  // D2: routing (1 block)
  route_kernel<<<1, 1024, 0, stream>>>(tope, ctrl, ptok, arow);
  // D3/D4: 128x256-tile GEMMs; grid = 8 XCDs x 68 slots >= 135*4 jobs max
  gemm1_kernel<<<8*68, 512, 0, stream>>>(xb, w1t, b1, ctrl, ptok, hbuf);
  gemm2_kernel<<<8*68, 512, 0, stream>>>(hbuf, w2t, b2, ctrl, ptok, yeb);
  // D5: combine
  combine_kernel<<<TOKENS/2, 256, 0, stream>>>(yeb, arow, topw, out);
}

// Round 11
// 265.912 us; speedup vs baseline: 1.7582x; 1.0726x over previous
//
#include <hip/hip_runtime.h>
#include <stdint.h>

#define TOKENS 8192
#define DIM    1024
#define NEXP   8
#define NASSIGN (TOKENS*2)
#define BK     64          // K-depth of LDS tile (32 KB total LDS)
#define NKT    (DIM/BK)    // 16 K-steps
#define G1BLK  1088        // gemm1 jobs (17 m-slots x 8 XCDs x 8 n-tiles)

// ---- control block indices (ints) ----
#define C_ROW   16   // 9: per-expert row prefix (row_start), [8]=16384
#define C_TILE  25   // 9: per-expert m-tile prefix
#define C_TOTAL 34   // total m-tiles

// ---- workspace layout (bytes) ----
#define WS_CTRL  0
#define WS_TOPE  1024
#define WS_TOPW  (WS_TOPE + NASSIGN*4)
#define WS_PTOK  (WS_TOPW + NASSIGN*4)
#define WS_AROW  (WS_PTOK + NASSIGN*4)
#define WS_XB    (WS_AROW + NASSIGN*4)                 // 256-aligned
#define WS_W1T   (WS_XB  + (size_t)TOKENS*DIM*2)
#define WS_W2T   (WS_W1T + (size_t)NEXP*DIM*DIM*2)
#define WS_H     (WS_W2T + (size_t)NEXP*DIM*DIM*2)
// ye (bf16, 16384x1024 = 32 MiB) overlays xb+w1t, both dead by gemm2 time:
#define WS_YE    WS_XB

#define WGLD (DIM + 4)   // padded LDS row for Wg^T staging (bank-conflict-free)

typedef __attribute__((ext_vector_type(8))) short short8;
typedef __attribute__((ext_vector_type(4))) float floatx4;

__device__ __forceinline__ uint32_t bfr(float f) {   // fp32 -> bf16 bits, RNE
  uint32_t v = __float_as_uint(f);
  return (v + 0x7FFFu + ((v >> 16) & 1u)) >> 16;
}
__device__ __forceinline__ float b2f(uint32_t u) { return __uint_as_float(u << 16); }

__device__ __forceinline__ void load_lds16(const void* g, void* l) {
  __builtin_amdgcn_global_load_lds(
      (const __attribute__((address_space(1))) uint32_t*)g,
      (__attribute__((address_space(3))) uint32_t*)l, 16, 0, 0);
}

// ---- shared convw tile body: dst[f][d] = bf16(src[d][f]), one 64x64 tile ----
__device__ __forceinline__ void convw_tile(
    const float* __restrict__ src, uint16_t* __restrict__ dst,
    int d0, int f0, uint16_t (*tile)[68], int t) {
  int col = t & 63, rb = (t >> 6) * 16;
  #pragma unroll
  for (int i = 0; i < 16; i++) {
    int dr = rb + i;
    tile[dr][col] = (uint16_t)bfr(src[(size_t)(d0+dr)*DIM + f0 + col]);
  }
  __syncthreads();
  int dg = t & 15, frb = t >> 4;         // 4 bf16 along d per thread, 16 f-rows/pass
  #pragma unroll
  for (int i = 0; i < 4; i++) {
    int fr = frb + i * 16;
    uint32_t c0 = tile[dg*4+0][fr], c1 = tile[dg*4+1][fr];
    uint32_t c2 = tile[dg*4+2][fr], c3 = tile[dg*4+3][fr];
    uint2 v;
    v.x = c0 | (c1 << 16);
    v.y = c2 | (c3 << 16);
    *(uint2*)&dst[(size_t)(f0+fr)*DIM + d0 + dg*4] = v;
  }
}

// ---------------- D1: gating + x->bf16 (blocks 0..2047) ∥ W1-transpose (2048..4095) ----
// W2's transpose is NOT here — it rides inside gemm1's dispatch (gemm1 doesn't
// read w2t; the gemm1->gemm2 boundary orders it). Merged single dispatch =
// measured-best prep structure (R0); splitting costs ~11us (R2/R4).
__global__ __launch_bounds__(256) void prep_kernel(
    const float* __restrict__ x, const float* __restrict__ Wg,
    const float* __restrict__ bg, float* __restrict__ gate_out,
    int* __restrict__ top_e, float* __restrict__ top_w,
    uint16_t* __restrict__ xb,
    const float* __restrict__ W1, uint16_t* __restrict__ W1T) {
  __shared__ __align__(16) char smem[NEXP * WGLD * 4];   // 32.9 KB union
  int t = threadIdx.x;

  if (blockIdx.x >= 2048) {
    int cb = blockIdx.x - 2048;            // 0..2047: W1 only
    int m  = cb >> 8;                      // 8 matrices
    int d0 = ((cb >> 4) & 15) * 64, f0 = (cb & 15) * 64;
    convw_tile(W1 + (size_t)m*DIM*DIM, W1T + (size_t)m*DIM*DIM,
               d0, f0, (uint16_t (*)[68])smem, t);
    return;
  }

  // ---------- gateconv: 1 wave per token, 4 tokens/block ----------
  float* wgs = (float*)smem;               // wgs[e*WGLD + d] = Wg[d][e]
  #pragma unroll
  for (int k = 0; k < 32; k++) {
    int i = k * 256 + t;                   // coalesced read of Wg flat
    float v = Wg[i];
    wgs[(i & 7) * WGLD + (i >> 3)] = v;    // bank = 4*(i&7)+(i>>3): 2-way, free
  }
  __syncthreads();

  int wave = t >> 6, lane = t & 63;
  int tok = blockIdx.x * 4 + wave;
  const float4* xr = (const float4*)(x + (size_t)tok * DIM);
  uint2* xw = (uint2*)(xb + (size_t)tok * DIM);

  float4 acc[NEXP];
  #pragma unroll
  for (int e = 0; e < NEXP; e++) acc[e] = make_float4(0.f, 0.f, 0.f, 0.f);

  #pragma unroll
  for (int c = 0; c < 4; c++) {
    float4 xv = xr[c * 64 + lane];
    uint2 o;
    o.x = bfr(xv.x) | (bfr(xv.y) << 16);
    o.y = bfr(xv.z) | (bfr(xv.w) << 16);
    xw[c * 64 + lane] = o;
    int d0 = (c * 64 + lane) * 4;
    #pragma unroll
    for (int e = 0; e < NEXP; e++) {
      float4 wv = *(const float4*)&wgs[e * WGLD + d0];
      acc[e].x = fmaf(xv.x, wv.x, acc[e].x);
      acc[e].y = fmaf(xv.y, wv.y, acc[e].y);
      acc[e].z = fmaf(xv.z, wv.z, acc[e].z);
      acc[e].w = fmaf(xv.w, wv.w, acc[e].w);
    }
  }
  float s[NEXP];
  #pragma unroll
  for (int e = 0; e < NEXP; e++) s[e] = (acc[e].x + acc[e].y) + (acc[e].z + acc[e].w);
  #pragma unroll
  for (int off = 32; off > 0; off >>= 1) {
    #pragma unroll
    for (int e = 0; e < NEXP; e++) s[e] += __shfl_xor(s[e], off);
  }
  if (lane == 0) {
    float lg[NEXP], p[NEXP];
    float mx = -1e30f;
    #pragma unroll
    for (int e = 0; e < NEXP; e++) { lg[e] = s[e] + bg[e]; mx = fmaxf(mx, lg[e]); }
    float sum = 0.f;
    #pragma unroll
    for (int e = 0; e < NEXP; e++) { p[e] = expf(lg[e] - mx); sum += p[e]; }
    float inv = 1.f / sum;
    #pragma unroll
    for (int e = 0; e < NEXP; e++) p[e] *= inv;
    float4* go = (float4*)(gate_out + (size_t)tok * NEXP);
    go[0] = make_float4(p[0], p[1], p[2], p[3]);
    go[1] = make_float4(p[4], p[5], p[6], p[7]);
    int i1 = 0;
    #pragma unroll
    for (int e = 1; e < NEXP; e++) if (p[e] > p[i1]) i1 = e;
    int i2 = (i1 == 0) ? 1 : 0;
    #pragma unroll
    for (int e = 0; e < NEXP; e++) if (e != i1 && p[e] > p[i2]) i2 = e;
    float ev = expf(p[i2] - p[i1]);        // softmax over the two top probs
    float w1 = 1.f / (1.f + ev), w2 = ev / (1.f + ev);
    top_e[2*tok]   = i1; top_e[2*tok+1] = i2;
    top_w[2*tok]   = w1; top_w[2*tok+1] = w2;
  }
}

// ---------------- deterministic routing: histogram + scan + scatter, 1 block (R0) ----------------
__global__ __launch_bounds__(1024) void route_kernel(
    const int* __restrict__ top_e, int* __restrict__ ctrl,
    int* __restrict__ ptok, int* __restrict__ arow) {
  __shared__ int sc[NEXP * 1024];      // 32 KB
  __shared__ int scnt[NEXP];
  __shared__ int rowstart[NEXP];
  int t = threadIdx.x;
  int e_loc[16];
  int cnt[NEXP];
  #pragma unroll
  for (int e = 0; e < NEXP; e++) cnt[e] = 0;
  #pragma unroll
  for (int j = 0; j < 16; j++) {
    int e = top_e[t * 16 + j];
    e_loc[j] = e;
    cnt[e]++;
  }
  #pragma unroll
  for (int e = 0; e < NEXP; e++) sc[e * 1024 + t] = cnt[e];
  __syncthreads();
  int wave = t >> 6, lane = t & 63;
  if (wave < NEXP) {
    int running = 0;
    for (int chunk = 0; chunk < 16; chunk++) {
      int idx = wave * 1024 + chunk * 64 + lane;
      int v = sc[idx];
      int incl = v;
      #pragma unroll
      for (int off = 1; off < 64; off <<= 1) {
        int u = __shfl_up(incl, off);
        if (lane >= off) incl += u;
      }
      sc[idx] = running + incl - v;    // exclusive prefix
      running += __shfl(incl, 63);
    }
    if (lane == 0) scnt[wave] = running;
  }
  __syncthreads();
  if (t == 0) {
    int rs = 0, ts = 0;
    for (int e = 0; e < NEXP; e++) {
      ctrl[C_ROW + e] = rs;
      ctrl[C_TILE + e] = ts;
      rowstart[e] = rs;
      int c = scnt[e];
      rs += c;
      ts += (c + 127) >> 7;
    }
    ctrl[C_ROW + NEXP] = rs;
    ctrl[C_TILE + NEXP] = ts;
    ctrl[C_TOTAL] = ts;
  }
  __syncthreads();
  int off[NEXP];
  #pragma unroll
  for (int e = 0; e < NEXP; e++) off[e] = rowstart[e] + sc[e * 1024 + t];
  #pragma unroll
  for (int j = 0; j < 16; j++) {
    int i = t * 16 + j;
    int e = e_loc[j];
    int pos = off[e]++;
    ptok[pos] = i >> 1;
    arow[i] = pos;
  }
}

// ---------------- GEMM block schedule ----------------
__device__ __forceinline__ bool sched_map(const int* ctrl, int bid,
                                          int& mtile, int& n0) {
  int total = ctrl[C_TOTAL];           // 128..135
  int spx = (total + 7) >> 3;          // slots per XCD: 16 or 17
  int xcd = bid & 7, j = bid >> 3;
  int slot = j >> 3;
  if (slot >= spx) return false;
  mtile = xcd * spx + slot;
  n0 = (j & 7) * 128;
  return mtile < total;
}

// ---------------- GEMM1 + W2-transpose in one dispatch ----------------
// Blocks 0..1087: h = relu(gather(xb) @ w1t + b1). Blocks 1088..3135: W2->w2t
// 64x64 transpose tiles (HBM-bound; fills gemm1's spare BW + barrier bubbles).
// gemm1 blocks dispatched first so they own the CUs. launch_bounds(256,2):
// measured L2 budget (R3: >2 blocks/CU breaks epilogue write-combining).
__global__ __launch_bounds__(256, 2) void gemm1_kernel(
    const uint16_t* __restrict__ xb, const uint16_t* __restrict__ w1t,
    const float* __restrict__ b1, const int* __restrict__ ctrl,
    const int* __restrict__ ptok, uint16_t* __restrict__ h,
    const float* __restrict__ W2, uint16_t* __restrict__ w2t) {
  __shared__ __align__(16) uint16_t As[128*BK];
  __shared__ __align__(16) uint16_t Bs[128*BK];
  int t = threadIdx.x;

  if (blockIdx.x >= G1BLK) {
    int cb = blockIdx.x - G1BLK;           // 0..2047: W2 only
    int m  = cb >> 8;                      // 8 matrices
    int d0 = ((cb >> 4) & 15) * 64, f0 = (cb & 15) * 64;
    convw_tile(W2 + (size_t)m*DIM*DIM, w2t + (size_t)m*DIM*DIM,
               d0, f0, (uint16_t (*)[68])As, t);
    return;
  }

  int mtile, n0;
  if (!sched_map(ctrl, blockIdx.x, mtile, n0)) return;
  int e = 0;
  #pragma unroll
  for (int k = 1; k < NEXP; k++) if (mtile >= ctrl[C_TILE + k]) e = k;
  int row0 = ctrl[C_ROW + e] + (mtile - ctrl[C_TILE + e]) * 128;
  int rend = ctrl[C_ROW + e + 1];

  int lane = t & 63, w = t >> 6;
  const uint16_t* gA[4];
  const uint16_t* gB[4];
  #pragma unroll
  for (int i = 0; i < 4; i++) {
    int s = i * 256 + t;               // LDS slot (16B units), 1024 per matrix
    int row = s >> 3, cs = s & 7;
    int gc = cs ^ (row & 7);           // inverse XOR swizzle applied at the source
    int ar = row0 + row; if (ar > NASSIGN-1) ar = NASSIGN-1;
    int tok = ptok[ar];
    gA[i] = xb  + (size_t)tok * DIM + gc*8;
    gB[i] = w1t + (size_t)e*DIM*DIM + (size_t)(n0 + row)*DIM + gc*8;
  }
  floatx4 acc[4][4];
  #pragma unroll
  for (int mi = 0; mi < 4; mi++)
    #pragma unroll
    for (int ni = 0; ni < 4; ni++) acc[mi][ni] = (floatx4)(0.f);

  int wm = w & 1, wn = w >> 1;
  int l15 = lane & 15, lq = lane >> 4;

  for (int kt = 0; kt < NKT; kt++) {
    #pragma unroll
    for (int i = 0; i < 4; i++) {
      load_lds16(gA[i], &As[(i*256 + t) * 8]);
      load_lds16(gB[i], &Bs[(i*256 + t) * 8]);
      gA[i] += BK; gB[i] += BK;
    }
    __syncthreads();
    #pragma unroll
    for (int ks = 0; ks < 2; ks++) {
      short8 a[4], b[4];
      #pragma unroll
      for (int mi = 0; mi < 4; mi++) {
        int row = wm*64 + mi*16 + l15;
        int slot = (ks*4 + lq) ^ (row & 7);
        a[mi] = *(const short8*)&As[row*BK + slot*8];
      }
      #pragma unroll
      for (int ni = 0; ni < 4; ni++) {
        int row = wn*64 + ni*16 + l15;
        int slot = (ks*4 + lq) ^ (row & 7);
        b[ni] = *(const short8*)&Bs[row*BK + slot*8];
      }
      #pragma unroll
      for (int mi = 0; mi < 4; mi++)
        #pragma unroll
        for (int ni = 0; ni < 4; ni++)
          acc[mi][ni] = __builtin_amdgcn_mfma_f32_16x16x32_bf16(a[mi], b[ni], acc[mi][ni], 0, 0, 0);
    }
    __syncthreads();
  }
  #pragma unroll
  for (int mi = 0; mi < 4; mi++) {
    #pragma unroll
    for (int r = 0; r < 4; r++) {
      int rt = wm*64 + mi*16 + lq*4 + r;
      int ar = row0 + rt;
      if (ar < rend) {
        #pragma unroll
        for (int ni = 0; ni < 4; ni++) {
          int n = n0 + wn*64 + ni*16 + l15;
          float v = acc[mi][ni][r] + b1[e*DIM + n];
          v = fmaxf(v, 0.f);
          h[(size_t)ar*DIM + n] = (uint16_t)bfr(v);
        }
      }
    }
  }
}

// ---------------- GEMM2: ye = h @ W2 + b2, bf16 dense rows (R4-verbatim) ----------------
__global__ __launch_bounds__(256, 2) void gemm2_kernel(
    const uint16_t* __restrict__ h, const uint16_t* __restrict__ w2t,
    const float* __restrict__ b2, const int* __restrict__ ctrl,
    uint16_t* __restrict__ yeb) {
  __shared__ __align__(16) uint16_t As[128*BK];
  __shared__ __align__(16) uint16_t Bs[128*BK];
  int mtile, n0;
  if (!sched_map(ctrl, blockIdx.x, mtile, n0)) return;
  int e = 0;
  #pragma unroll
  for (int k = 1; k < NEXP; k++) if (mtile >= ctrl[C_TILE + k]) e = k;
  int row0 = ctrl[C_ROW + e] + (mtile - ctrl[C_TILE + e]) * 128;
  int rend = ctrl[C_ROW + e + 1];

  int t = threadIdx.x, lane = t & 63, w = t >> 6;
  const uint16_t* gA[4];
  const uint16_t* gB[4];
  #pragma unroll
  for (int i = 0; i < 4; i++) {
    int s = i * 256 + t;
    int row = s >> 3, cs = s & 7;
    int gc = cs ^ (row & 7);
    int ar = row0 + row; if (ar > NASSIGN-1) ar = NASSIGN-1;
    gA[i] = h   + (size_t)ar * DIM + gc*8;
    gB[i] = w2t + (size_t)e*DIM*DIM + (size_t)(n0 + row)*DIM + gc*8;
  }
  floatx4 acc[4][4];
  #pragma unroll
  for (int mi = 0; mi < 4; mi++)
    #pragma unroll
    for (int ni = 0; ni < 4; ni++) acc[mi][ni] = (floatx4)(0.f);

  int wm = w & 1, wn = w >> 1;
  int l15 = lane & 15, lq = lane >> 4;

  for (int kt = 0; kt < NKT; kt++) {
    #pragma unroll
    for (int i = 0; i < 4; i++) {
      load_lds16(gA[i], &As[(i*256 + t) * 8]);
      load_lds16(gB[i], &Bs[(i*256 + t) * 8]);
      gA[i] += BK; gB[i] += BK;
    }
    __syncthreads();
    #pragma unroll
    for (int ks = 0; ks < 2; ks++) {
      short8 a[4], b[4];
      #pragma unroll
      for (int mi = 0; mi < 4; mi++) {
        int row = wm*64 + mi*16 + l15;
        int slot = (ks*4 + lq) ^ (row & 7);
        a[mi] = *(const short8*)&As[row*BK + slot*8];
      }
      #pragma unroll
      for (int ni = 0; ni < 4; ni++) {
        int row = wn*64 + ni*16 + l15;
        int slot = (ks*4 + lq) ^ (row & 7);
        b[ni] = *(const short8*)&Bs[row*BK + slot*8];
      }
      #pragma unroll
      for (int mi = 0; mi < 4; mi++)
        #pragma unroll
        for (int ni = 0; ni < 4; ni++)
          acc[mi][ni] = __builtin_amdgcn_mfma_f32_16x16x32_bf16(a[mi], b[ni], acc[mi][ni], 0, 0, 0);
    }
    __syncthreads();
  }
  #pragma unroll
  for (int mi = 0; mi < 4; mi++) {
    #pragma unroll
    for (int r = 0; r < 4; r++) {
      int rt = wm*64 + mi*16 + lq*4 + r;
      int ar = row0 + rt;
      if (ar < rend) {
        #pragma unroll
        for (int ni = 0; ni < 4; ni++) {
          int n = n0 + wn*64 + ni*16 + l15;
          float v = acc[mi][ni][r] + b2[e*DIM + n];
          yeb[(size_t)ar*DIM + n] = (uint16_t)bfr(v);
        }
      }
    }
  }
}

// ---------------- combine: y[tok] = w0*ye[r0] + w1*ye[r1], 2 tokens/block ----------------
__global__ __launch_bounds__(256) void combine_kernel(
    const uint16_t* __restrict__ yeb, const int* __restrict__ arow,
    const float* __restrict__ top_w, float* __restrict__ y) {
  int t = threadIdx.x;
  int tok = blockIdx.x * 2 + (t >> 7);     // 128 threads per token
  int i = t & 127;                          // 8 bf16 per thread
  int r0 = arow[2*tok], r1 = arow[2*tok+1];
  float w0 = top_w[2*tok], w1 = top_w[2*tok+1];
  const uint4* a = (const uint4*)(yeb + (size_t)r0 * DIM);
  const uint4* b = (const uint4*)(yeb + (size_t)r1 * DIM);
  uint4 av = a[i], bv = b[i];
  float4* yo = (float4*)(y + (size_t)tok * DIM + i * 8);
  float4 o0, o1;
  o0.x = w0 * b2f(av.x & 0xFFFFu) + w1 * b2f(bv.x & 0xFFFFu);
  o0.y = w0 * b2f(av.x >> 16)     + w1 * b2f(bv.x >> 16);
  o0.z = w0 * b2f(av.y & 0xFFFFu) + w1 * b2f(bv.y & 0xFFFFu);
  o0.w = w0 * b2f(av.y >> 16)     + w1 * b2f(bv.y >> 16);
  o1.x = w0 * b2f(av.z & 0xFFFFu) + w1 * b2f(bv.z & 0xFFFFu);
  o1.y = w0 * b2f(av.z >> 16)     + w1 * b2f(bv.z >> 16);
  o1.z = w0 * b2f(av.w & 0xFFFFu) + w1 * b2f(bv.w & 0xFFFFu);
  o1.w = w0 * b2f(av.w >> 16)     + w1 * b2f(bv.w >> 16);
  yo[0] = o0;
  yo[1] = o1;
}

extern "C" void kernel_launch(void* const* d_in, const int* in_sizes, int n_in,
                              void* d_out, int out_size, void* d_ws, size_t ws_size,
                              hipStream_t stream) {
  const float* x  = (const float*)d_in[0];
  const float* Wg = (const float*)d_in[1];
  const float* bg = (const float*)d_in[2];
  const float* W1 = (const float*)d_in[3];
  const float* b1 = (const float*)d_in[4];
  const float* W2 = (const float*)d_in[5];
  const float* b2 = (const float*)d_in[6];
  float* out = (float*)d_out;                      // [y: 8192*1024][gate: 8192*8]
  char* ws = (char*)d_ws;

  int*      ctrl = (int*)(ws + WS_CTRL);
  int*      tope = (int*)(ws + WS_TOPE);
  float*    topw = (float*)(ws + WS_TOPW);
  int*      ptok = (int*)(ws + WS_PTOK);
  int*      arow = (int*)(ws + WS_AROW);
  uint16_t* xb   = (uint16_t*)(ws + WS_XB);
  uint16_t* w1t  = (uint16_t*)(ws + WS_W1T);
  uint16_t* w2t  = (uint16_t*)(ws + WS_W2T);
  uint16_t* hbuf = (uint16_t*)(ws + WS_H);
  uint16_t* yeb  = (uint16_t*)(ws + WS_YE);        // overlays xb+w1t (dead by then)

  // D1: gating + x->bf16 + W1 transpose only (4096 blocks, merged)
  prep_kernel<<<4096, 256, 0, stream>>>(x, Wg, bg, out + (size_t)TOKENS*DIM,
                                        tope, topw, xb, W1, w1t);
  // D2: routing (1 block; exposed ~10us — measured cheaper than any hiding)
  route_kernel<<<1, 1024, 0, stream>>>(tope, ctrl, ptok, arow);
  // D3: gemm1 (blocks 0..1087) + W2 transpose (blocks 1088..3135) overlapped
  gemm1_kernel<<<G1BLK + 2048, 256, 0, stream>>>(xb, w1t, b1, ctrl, ptok, hbuf,
                                                 W2, w2t);
  // D4: gemm2 (w2t guaranteed complete by D3->D4 boundary)
  gemm2_kernel<<<136*8, 256, 0, stream>>>(hbuf, w2t, b2, ctrl, yeb);
  // D5: combine
  combine_kernel<<<TOKENS/2, 256, 0, stream>>>(yeb, arow, topw, out);
}